// Round 9
// baseline (1199.268 us; speedup 1.0000x reference)
//
#include <hip/hip_runtime.h>
#include <hip/hip_fp16.h>
#include <stdint.h>

#define HH 100
#define WW 100
#define NPIX 10000
#define CIN 1024
#define COUT 1024
#define NA 9
#define NANCH 90000
#define PRE 6000
#define POST 300
#define SORTN 131072
#define MASKW 96
#define NW 94
#define K9 9216          // CIN*9
#define SPAD 10404       // 102*102 padded pixel rows
#define WSCALE 1024.0f   // exact pow2 pre-scale for w split (avoids fp16 subnormals)
#define KH 48            // padded head output count (9 cls + 36 box + 3 pad)

// conv tiling: 256co x 160px, 512 thr (8 waves, 2/SIMD), 3 LDS buffers,
// counted-vmcnt 2-step-lookahead pipeline (T3/T4), unroll-3 static buffers.
#define PXT 160
#define BUFB 53248       // A1@0(16K) A2@16384(16K) B1@32768(10K) B2@43008(10K)
#define NSTEP 288        // 9 taps x 32 ci-steps (divisible by 3)

#define HEADB 157        // rpn_head real blocks = (NPIX+63)/64

typedef unsigned short u16;
typedef _Float16 f16x8 __attribute__((ext_vector_type(8)));
typedef float f32x4 __attribute__((ext_vector_type(4)));

__device__ __forceinline__ void gload16(const u16* g, char* l)
{
    __builtin_amdgcn_global_load_lds((const void*)g, (void*)l, 16, 0, 0);
}

// ---------------------------------------------------------------------------
// xsplit (+fused border zeroing)
// ---------------------------------------------------------------------------
__global__ __launch_bounds__(256) void xsplit(
    const float* __restrict__ x, u16* __restrict__ xt1, u16* __restrict__ xt2)
{
    __shared__ unsigned sh[32][257];   // [px_local][ci_local]: h1<<16 | h2
    const int t = threadIdx.x;
    if (blockIdx.x >= 313) {
        int idx = (blockIdx.x - 313) * 4 + blockIdx.y;   // 0..403
        int spx;
        if (idx < 102) spx = idx;
        else if (idx < 204) spx = 10302 + (idx - 102);
        else { int k = idx - 204; spx = (1 + (k >> 1)) * 102 + (k & 1) * 101; }
        size_t o = (size_t)spx * 1024 + t * 4;
        *(ushort4*)&xt1[o] = make_ushort4(0, 0, 0, 0);
        *(ushort4*)&xt2[o] = make_ushort4(0, 0, 0, 0);
        return;
    }
    const int px0 = blockIdx.x * 32;
    const int ci0 = blockIdx.y * 256;
    for (int it = 0; it < 32; ++it) {
        int idx = it * 256 + t;
        int a = idx >> 5, b = idx & 31;
        int p = px0 + b;
        float v = (p < NPIX) ? x[(size_t)(ci0 + a) * NPIX + p] : 0.f;
        __half h1 = __float2half_rn(v);
        __half h2 = __float2half_rn(v - __half2float(h1));
        sh[b][a] = ((unsigned)__half_as_ushort(h1) << 16) | __half_as_ushort(h2);
    }
    __syncthreads();
    for (int it = 0; it < 8; ++it) {
        int u = it * 256 + t;
        int pl = u >> 6, cq = u & 63;
        int p = px0 + pl;
        if (p >= NPIX) continue;
        int r = p / 100, c = p - r * 100;
        int spx = (r + 1) * 102 + (c + 1);
        unsigned w0 = sh[pl][cq * 4 + 0], w1 = sh[pl][cq * 4 + 1];
        unsigned w2 = sh[pl][cq * 4 + 2], w3 = sh[pl][cq * 4 + 3];
        ushort4 v1 = make_ushort4((u16)(w0 >> 16), (u16)(w1 >> 16), (u16)(w2 >> 16), (u16)(w3 >> 16));
        ushort4 v2 = make_ushort4((u16)(w0 & 0xffff), (u16)(w1 & 0xffff), (u16)(w2 & 0xffff), (u16)(w3 & 0xffff));
        size_t o = (size_t)spx * 1024 + ci0 + cq * 4;
        *(ushort4*)&xt1[o] = v1;
        *(ushort4*)&xt2[o] = v2;
    }
}

// ---------------------------------------------------------------------------
// wsplit (+fused wh_prep)
// ---------------------------------------------------------------------------
__global__ __launch_bounds__(256) void wsplit(
    const float* __restrict__ w1, u16* __restrict__ wp1, u16* __restrict__ wp2,
    const float* __restrict__ wcls, const float* __restrict__ wbox,
    float* __restrict__ wh)
{
    __shared__ float sw[K9];
    const int t = threadIdx.x;
    if (blockIdx.x >= COUT) {
        int e = (blockIdx.x - COUT) * 256 + t;     // over CIN*KH
        if (e < CIN * KH) {
            int c = e / KH, k = e - c * KH;
            float v = 0.f;
            if (k < 9) v = wcls[k * CIN + c];
            else if (k < 45) v = wbox[(k - 9) * CIN + c];
            wh[e] = v;
        }
        return;
    }
    const int co = blockIdx.x;
    for (int it = 0; it < 36; ++it)
        sw[it * 256 + t] = w1[(size_t)co * K9 + it * 256 + t];
    __syncthreads();
    for (int tap = 0; tap < 9; ++tap) {
        for (int it = 0; it < 4; ++it) {
            int ci = it * 256 + t;
            float v = sw[ci * 9 + tap] * WSCALE;
            __half h1 = __float2half_rn(v);
            __half h2 = __float2half_rn(v - __half2float(h1));
            size_t o = (size_t)tap * (COUT * 1024) + (size_t)co * 1024 + ci;
            wp1[o] = __half_as_ushort(h1);
            wp2[o] = __half_as_ushort(h2);
        }
    }
}

// ---------------------------------------------------------------------------
// conv_mfma: 3x3 conv via fp16-split MFMA. Block 256co x 160px, 512 thr,
// wave tile 64x80, 8 waves. 3-buffer LDS, 2-step lookahead, per-wave counted
// vmcnt (8 for 8-issue waves, 6 for 6-issue), unroll-3 with static buffer
// indices, setprio(1) around compute (T5).
// ---------------------------------------------------------------------------
__global__ __launch_bounds__(512, 1) void conv_mfma(
    const u16* __restrict__ xt1, const u16* __restrict__ xt2,
    const u16* __restrict__ wp1, const u16* __restrict__ wp2,
    const float* __restrict__ b1, float* __restrict__ y)
{
    __shared__ __align__(16) char lds[3 * BUFB];   // 156 KiB
    const int t = threadIdx.x;
    const int co0 = blockIdx.x * 256;
    const int px0 = blockIdx.y * PXT;
    const int lane = t & 63;
    const int wv = __builtin_amdgcn_readfirstlane(t >> 6);   // 0..7
    const int wm = (wv >> 1) * 64;          // co sub-tile: 0,64,128,192
    const int wn = (wv & 1) * 80;           // px sub-tile: 0,80

    const int qs = (lane & 3) ^ ((lane >> 3) & 3);

    // A: wave wv stages co rows [wv*32, wv*32+32) for both planes (4 issues)
    const int ar0 = wv * 32, ar1 = wv * 32 + 16;
    const size_t aOff0 = (size_t)(co0 + ar0 + (lane >> 2)) * 1024 + qs * 8;
    const size_t aOff1 = (size_t)(co0 + ar1 + (lane >> 2)) * 1024 + qs * 8;

    // B: unit u covers rows [u*16,u*16+16); wave wv takes u=wv and (wv<2) 8+wv
    const int nbu = (wv < 2) ? 2 : 1;
    size_t bOff[2]; int bLds[2];
#pragma unroll
    for (int s = 0; s < 2; ++s) {
        int r0 = (wv + 8 * s) * 16;
        if (r0 >= PXT) r0 = 0;                    // unused slot
        int p = px0 + r0 + (lane >> 2);
        if (p > NPIX - 1) p = NPIX - 1;
        int rr = p / 100, cc = p - rr * 100;
        bOff[s] = (size_t)((rr + 1) * 102 + cc + 1) * 1024 + qs * 8;
        bLds[s] = r0 * 64;
    }

    const int qf = ((lane >> 4) ^ (((lane & 15) >> 1) & 3)) * 16;
    const int fA = (wm + (lane & 15)) * 64 + qf;
    const int fB = 32768 + (wn + (lane & 15)) * 64 + qf;

    f32x4 acc[4][5] = {};

    auto STAGE = [&](int buf, int step) {
        char* lb = lds + buf * BUFB;
        const int tap = step >> 5;
        const int ci0 = (step & 31) << 5;
        const int dy = (tap * 11) >> 5;            // tap/3 for 0..8
        const int tsh = (dy - 1) * 102 + (tap - dy * 3) - 1;
        const size_t adelta = (size_t)tap * 1048576 + ci0;
        const ptrdiff_t bdelta = (ptrdiff_t)tsh * 1024 + ci0;
        gload16(wp1 + aOff0 + adelta, lb + ar0 * 64);
        gload16(wp1 + aOff1 + adelta, lb + ar1 * 64);
        gload16(wp2 + aOff0 + adelta, lb + 16384 + ar0 * 64);
        gload16(wp2 + aOff1 + adelta, lb + 16384 + ar1 * 64);
#pragma unroll
        for (int s = 0; s < 2; ++s) {
            if (s < nbu) {
                gload16(xt1 + (ptrdiff_t)bOff[s] + bdelta, lb + 32768 + bLds[s]);
                gload16(xt2 + (ptrdiff_t)bOff[s] + bdelta, lb + 43008 + bLds[s]);
            }
        }
    };

    auto COMPUTE = [&](int buf) {
        const char* lb = lds + buf * BUFB;
        f16x8 A1[4], A2[4], B1[5], B2[5];
#pragma unroll
        for (int mi = 0; mi < 4; ++mi) {
            A1[mi] = *(const f16x8*)(lb + fA + mi * 1024);
            A2[mi] = *(const f16x8*)(lb + 16384 + fA + mi * 1024);
        }
#pragma unroll
        for (int ni = 0; ni < 5; ++ni) {
            B1[ni] = *(const f16x8*)(lb + fB + ni * 1024);
            B2[ni] = *(const f16x8*)(lb + fB + 10240 + ni * 1024);
        }
#pragma unroll
        for (int mi = 0; mi < 4; ++mi)
#pragma unroll
            for (int ni = 0; ni < 5; ++ni) {
                acc[mi][ni] = __builtin_amdgcn_mfma_f32_16x16x32_f16(A1[mi], B1[ni], acc[mi][ni], 0, 0, 0);
                acc[mi][ni] = __builtin_amdgcn_mfma_f32_16x16x32_f16(A1[mi], B2[ni], acc[mi][ni], 0, 0, 0);
                acc[mi][ni] = __builtin_amdgcn_mfma_f32_16x16x32_f16(A2[mi], B1[ni], acc[mi][ni], 0, 0, 0);
            }
    };

    // per-wave counted wait: N = own stage issue count (8 for wv<2, else 6).
    // In-order retirement => outstanding<=N implies every older stage retired.
    auto WAITC = [&]() {
        if (wv < 2) asm volatile("s_waitcnt vmcnt(8)" ::: "memory");
        else        asm volatile("s_waitcnt vmcnt(6)" ::: "memory");
    };
    auto WAIT0 = [&]() { asm volatile("s_waitcnt vmcnt(0)" ::: "memory"); };

    STAGE(0, 0);
    STAGE(1, 1);
    WAITC();
    __builtin_amdgcn_s_barrier();

    for (int k = 0; k < NSTEP; k += 3) {
        // slot A: compute buf0 (step k), stage buf2 (step k+2)
        if (k + 2 < NSTEP) STAGE(2, k + 2);
        __builtin_amdgcn_s_setprio(1);
        COMPUTE(0);
        __builtin_amdgcn_s_setprio(0);
        if (k >= NSTEP - 2) WAIT0(); else WAITC();
        __builtin_amdgcn_s_barrier();
        // slot B: compute buf1 (step k+1), stage buf0 (step k+3)
        if (k + 3 < NSTEP) STAGE(0, k + 3);
        __builtin_amdgcn_s_setprio(1);
        COMPUTE(1);
        __builtin_amdgcn_s_setprio(0);
        if (k + 1 >= NSTEP - 2) WAIT0(); else WAITC();
        __builtin_amdgcn_s_barrier();
        // slot C: compute buf2 (step k+2), stage buf1 (step k+4)
        if (k + 4 < NSTEP) STAGE(1, k + 4);
        __builtin_amdgcn_s_setprio(1);
        COMPUTE(2);
        __builtin_amdgcn_s_setprio(0);
        if (k + 2 >= NSTEP - 2) WAIT0(); else WAITC();
        __builtin_amdgcn_s_barrier();
    }

    // epilogue: D row=(lane>>4)*4+reg (co), col=lane&15 (px); descale+bias+relu
    const int q4 = (lane >> 4) * 4, nl = lane & 15;
    const float inv = 1.0f / WSCALE;
#pragma unroll
    for (int mi = 0; mi < 4; ++mi) {
        const int cob = co0 + wm + mi * 16 + q4;
        const float bb0 = b1[cob + 0], bb1 = b1[cob + 1];
        const float bb2 = b1[cob + 2], bb3 = b1[cob + 3];
#pragma unroll
        for (int ni = 0; ni < 5; ++ni) {
            const int px = px0 + wn + ni * 16 + nl;
            if (px < NPIX) {
                y[(size_t)(cob + 0) * NPIX + px] = fmaxf(acc[mi][ni][0] * inv + bb0, 0.f);
                y[(size_t)(cob + 1) * NPIX + px] = fmaxf(acc[mi][ni][1] * inv + bb1, 0.f);
                y[(size_t)(cob + 2) * NPIX + px] = fmaxf(acc[mi][ni][2] * inv + bb2, 0.f);
                y[(size_t)(cob + 3) * NPIX + px] = fmaxf(acc[mi][ni][3] * inv + bb3, 0.f);
            }
        }
    }
}

// ---------------------------------------------------------------------------
// rpn_head (pixel-major, +fused key padding)
// ---------------------------------------------------------------------------
__global__ __launch_bounds__(256) void rpn_head(
    const float* __restrict__ y, const float* __restrict__ wh,
    const float* __restrict__ bcls, const float* __restrict__ bbox,
    const float* __restrict__ am, const int* __restrict__ ishape,
    float* __restrict__ out_scores, float* __restrict__ out_deltas,
    float4* __restrict__ boxes, unsigned long long* __restrict__ keys)
{
    __shared__ float red[4][64][KH + 1];
    const int t = threadIdx.x;
    if (blockIdx.x >= HEADB) {
        int i = NANCH + (blockIdx.x - HEADB) * 256 + t;
        if (i < SORTN) keys[i] = 0ull;
        return;
    }
    const int lane = t & 63;
    const int q = __builtin_amdgcn_readfirstlane(t >> 6);
    const int p = blockIdx.x * 64 + lane;
    const int pp = (p < NPIX) ? p : (NPIX - 1);

    float acc[45];
#pragma unroll
    for (int k = 0; k < 45; ++k) acc[k] = 0.f;

    const float* __restrict__ yq  = y  + (size_t)q * 256 * NPIX + pp;
    const float* __restrict__ whq = wh + (size_t)q * 256 * KH;
    for (int c = 0; c < 256; ++c) {
        float yv = yq[(size_t)c * NPIX];
        const float* wr = whq + c * KH;
#pragma unroll
        for (int k = 0; k < 45; ++k) acc[k] += yv * wr[k];
    }

#pragma unroll
    for (int k = 0; k < 45; ++k) red[q][lane][k] = acc[k];
    __syncthreads();

    if (t >= 64 || p >= NPIX) return;

    float s[45];
#pragma unroll
    for (int k = 0; k < 45; ++k)
        s[k] = (red[0][lane][k] + red[1][lane][k]) + (red[2][lane][k] + red[3][lane][k]);

    const float imh = (float)ishape[1], imw = (float)ishape[2];
#pragma unroll
    for (int a = 0; a < 9; ++a) {
        const int i = p * NA + a;
        float logit = s[a] + bcls[a];
        float score = 1.f / (1.f + expf(-logit));
        float d0 = s[9 + a * 4 + 0] + bbox[a * 4 + 0];
        float d1 = s[9 + a * 4 + 1] + bbox[a * 4 + 1];
        float d2 = s[9 + a * 4 + 2] + bbox[a * 4 + 2];
        float d3 = s[9 + a * 4 + 3] + bbox[a * 4 + 3];
        out_scores[i] = score;
        out_deltas[i * 4 + 0] = d0;
        out_deltas[i * 4 + 1] = d1;
        out_deltas[i * 4 + 2] = d2;
        out_deltas[i * 4 + 3] = d3;

        float cy = am[i * 4 + 0], cx = am[i * 4 + 1];
        float ah = am[i * 4 + 2], aw = am[i * 4 + 3];
        float ctry = cy + d0 * ah, ctrx = cx + d1 * aw;
        float hh = ah * expf(d2), ww = aw * expf(d3);
        float y1 = fmaxf(ctry - 0.5f * hh, 0.f);
        float x1 = fmaxf(ctrx - 0.5f * ww, 0.f);
        float y2 = fminf(ctry + 0.5f * hh, imh);
        float x2 = fminf(ctrx + 0.5f * ww, imw);
        boxes[i] = make_float4(y1, x1, y2, x2);
        unsigned sb = __float_as_uint(score);
        keys[i] = ((unsigned long long)sb << 32) | (unsigned)i;
    }
}

// ---------------------------------------------------------------------------
// Bitonic sort (descending) of SORTN u64 keys — 16384-element LDS windows
// (128 KiB, 1024 thr). local16k covers L<=16384; lmerge16k covers d<=8192;
// gpass for d>=16384. Final lmerge16k block 0 fuses the top-PRE gather.
// ---------------------------------------------------------------------------
__global__ __launch_bounds__(1024) void bitonic_local16k(unsigned long long* keys)
{
    __shared__ unsigned long long s[16384];
    const int base = blockIdx.x * 16384, t = threadIdx.x;
    for (int k = t; k < 16384; k += 1024) s[k] = keys[base + k];
    for (int L = 2; L <= 16384; L <<= 1) {
        for (int d = L >> 1; d >= 1; d >>= 1) {
            __syncthreads();
            for (int pr = t; pr < 8192; pr += 1024) {
                int i = ((pr & ~(d - 1)) << 1) | (pr & (d - 1));
                int j = i + d;
                bool desc = (((base + i) & L) == 0);
                unsigned long long va = s[i], vb = s[j];
                bool sw = desc ? (va < vb) : (va > vb);
                if (sw) { s[i] = vb; s[j] = va; }
            }
        }
    }
    __syncthreads();
    for (int k = t; k < 16384; k += 1024) keys[base + k] = s[k];
}

__global__ __launch_bounds__(256) void bitonic_gpass(unsigned long long* keys, int L, int d)
{
    int pr = blockIdx.x * 256 + threadIdx.x;
    int i = ((pr & ~(d - 1)) << 1) | (pr & (d - 1));
    int j = i + d;
    bool desc = ((i & L) == 0);
    unsigned long long va = keys[i], vb = keys[j];
    bool sw = desc ? (va < vb) : (va > vb);
    if (sw) { keys[i] = vb; keys[j] = va; }
}

__global__ __launch_bounds__(1024) void bitonic_lmerge16k(
    unsigned long long* keys, int L,
    const float4* __restrict__ boxes, float4* __restrict__ box_s,
    unsigned long long* __restrict__ validw)
{
    __shared__ unsigned long long s[16384];
    const int base = blockIdx.x * 16384, t = threadIdx.x;
    for (int k = t; k < 16384; k += 1024) s[k] = keys[base + k];
    const bool desc = ((base & L) == 0);
    for (int d = 8192; d >= 1; d >>= 1) {
        __syncthreads();
        for (int pr = t; pr < 8192; pr += 1024) {
            int i = ((pr & ~(d - 1)) << 1) | (pr & (d - 1));
            int j = i + d;
            unsigned long long va = s[i], vb = s[j];
            bool sw = desc ? (va < vb) : (va > vb);
            if (sw) { s[i] = vb; s[j] = va; }
        }
    }
    __syncthreads();
    for (int k = t; k < 16384; k += 1024) keys[base + k] = s[k];
    // final merge, block 0: s[0..16383] is the global top-16384 (descending) —
    // fused gather of the top-PRE boxes + min-size valid ballot.
    if (L == SORTN && blockIdx.x == 0) {
        for (int k = t; k < 6144; k += 1024) {
            bool valid = false;
            if (k < PRE) {
                unsigned idx = (unsigned)(s[k] & 0xffffffffull);
                float4 b = boxes[idx];
                box_s[k] = b;
                valid = ((b.z - b.x) >= 16.f) && ((b.w - b.y) >= 16.f);
            }
            unsigned long long bal = __ballot(valid);
            if ((t & 63) == 0) validw[k >> 6] = bal;
        }
    }
}

// ---------------------------------------------------------------------------
__global__ __launch_bounds__(128) void nms_mask(
    const float4* __restrict__ box_s, unsigned long long* __restrict__ mask)
{
    const int i = blockIdx.x;
    const int w = threadIdx.x;
    if (w >= NW) return;
    float4 bi = box_s[i];
    float areai = (bi.z - bi.x) * (bi.w - bi.y);
    unsigned long long m = 0ull;
    const int j0 = w * 64;
    if (j0 + 63 > i) {
#pragma unroll 4
        for (int b = 0; b < 64; ++b) {
            int j = j0 + b;
            if (j <= i || j >= PRE) continue;
            float4 bj = box_s[j];
            float areaj = (bj.z - bj.x) * (bj.w - bj.y);
            float iy1 = fmaxf(bi.x, bj.x), ix1 = fmaxf(bi.y, bj.y);
            float iy2 = fminf(bi.z, bj.z), ix2 = fminf(bi.w, bj.w);
            float inter = fmaxf(iy2 - iy1, 0.f) * fmaxf(ix2 - ix1, 0.f);
            float iou = inter / (areai + areaj - inter + 1e-8f);
            if (iou > 0.7f) m |= (1ull << b);
        }
    }
    mask[(size_t)i * MASKW + w] = m;
}

// ---------------------------------------------------------------------------
// nms_scan (+fused out_gather)
// ---------------------------------------------------------------------------
__global__ __launch_bounds__(256) void nms_scan_out(
    const unsigned long long* __restrict__ mask,
    const unsigned long long* __restrict__ validw,
    const float4* __restrict__ box_s, float* __restrict__ outp)
{
    __shared__ unsigned long long kw_s[NW];
    __shared__ int prefix[NW];
    const int t = threadIdx.x;
    if (t < 64) {
        const int l = t;
        unsigned long long r0 = ~validw[l];
        unsigned long long r1 = (l < NW - 64) ? ~validw[64 + l] : ~0ull;
        unsigned long long p0[16], p1[16];
#pragma unroll
        for (int k = 0; k < 16; ++k) {
            p0[k] = mask[(size_t)k * MASKW + l];
            p1[k] = (l < NW - 64) ? mask[(size_t)k * MASKW + 64 + l] : 0ull;
        }
        int kept = 0;
        for (int w = 0; w < NW && kept < POST; ++w) {
            unsigned long long Wc = (w < 64) ? __shfl(r0, w) : __shfl(r1, w - 64);
#pragma unroll 16
            for (int b = 0; b < 64; ++b) {
                int i = w * 64 + b;
                if (i >= PRE) break;
                int slot = i & 15;
                unsigned long long m0 = p0[slot], m1 = p1[slot];
                int nxt = i + 16;
                if (nxt < PRE) {
                    p0[slot] = mask[(size_t)nxt * MASKW + l];
                    p1[slot] = (l < NW - 64) ? mask[(size_t)nxt * MASKW + 64 + l] : 0ull;
                }
                if (!((Wc >> b) & 1ull)) {
                    r0 |= m0; r1 |= m1;
                    Wc = (w < 64) ? __shfl(r0, w) : __shfl(r1, w - 64);
                    ++kept;
                }
            }
        }
        kw_s[l] = ~r0;
        if (l < NW - 64) kw_s[64 + l] = ~r1;
    }
    __syncthreads();
    if (t == 0) {
        int cum = 0;
        for (int w = 0; w < NW; ++w) { prefix[w] = cum; cum += __popcll(kw_s[w]); }
    }
    for (int k = t; k < POST * 4; k += 256) outp[k] = 0.f;
    __syncthreads();
    for (int i = t; i < PRE; i += 256) {
        int w = i >> 6, b = i & 63;
        unsigned long long kw = kw_s[w];
        if ((kw >> b) & 1ull) {
            int rank = prefix[w] + __popcll(kw & ((1ull << b) - 1ull));
            if (rank < POST) {
                float4 bx = box_s[i];
                outp[rank * 4 + 0] = bx.x;
                outp[rank * 4 + 1] = bx.y;
                outp[rank * 4 + 2] = bx.z;
                outp[rank * 4 + 3] = bx.w;
            }
        }
    }
}

// ---------------------------------------------------------------------------
extern "C" void kernel_launch(void* const* d_in, const int* in_sizes, int n_in,
                              void* d_out, int out_size, void* d_ws, size_t ws_size,
                              hipStream_t stream)
{
    const float* x      = (const float*)d_in[0];
    const int*   ishape = (const int*)  d_in[1];
    const float* am     = (const float*)d_in[2];
    const float* w1   = (const float*)d_in[6];
    const float* b1   = (const float*)d_in[7];
    const float* wcls = (const float*)d_in[8];
    const float* bcls = (const float*)d_in[9];
    const float* wbox = (const float*)d_in[10];
    const float* bbox = (const float*)d_in[11];
    float* out = (float*)d_out;

    char* ws = (char*)d_ws;
    size_t off = 0;
    float* y  = (float*)(ws + off);  off += (size_t)COUT * NPIX * 4;
    u16* xt1  = (u16*)(ws + off);    off += (size_t)SPAD * 1024 * 2;
    u16* xt2  = (u16*)(ws + off);    off += (size_t)SPAD * 1024 * 2;
    u16* wp1  = (u16*)(ws + off);    off += (size_t)9 * COUT * 1024 * 2;
    u16* wp2  = (u16*)(ws + off);    off += (size_t)9 * COUT * 1024 * 2;
    float4* boxes = (float4*)(ws + off);              off += (size_t)NANCH * 16;
    unsigned long long* keys = (unsigned long long*)(ws + off); off += (size_t)SORTN * 8;
    float4* box_s = (float4*)(ws + off);              off += (size_t)PRE * 16;
    unsigned long long* validw = (unsigned long long*)(ws + off); off += 96 * 8;
    unsigned long long* maskb  = (unsigned long long*)(ws + off); off += (size_t)PRE * MASKW * 8;
    float* wh = (float*)(ws + off);  off += (size_t)CIN * KH * 4;

    xsplit<<<dim3(414, 4), 256, 0, stream>>>(x, xt1, xt2);
    wsplit<<<COUT + (CIN * KH + 255) / 256, 256, 0, stream>>>(w1, wp1, wp2, wcls, wbox, wh);
    conv_mfma<<<dim3(4, (NPIX + PXT - 1) / PXT), 512, 0, stream>>>(xt1, xt2, wp1, wp2, b1, y);
    rpn_head<<<HEADB + (SORTN - NANCH + 255) / 256, 256, 0, stream>>>(
        y, wh, bcls, bbox, am, ishape, out, out + NANCH, boxes, keys);
    bitonic_local16k<<<SORTN / 16384, 1024, 0, stream>>>(keys);
    for (int L = 32768; L <= SORTN; L <<= 1) {
        for (int d = L >> 1; d >= 16384; d >>= 1)
            bitonic_gpass<<<SORTN / 512, 256, 0, stream>>>(keys, L, d);
        bitonic_lmerge16k<<<SORTN / 16384, 1024, 0, stream>>>(keys, L, boxes, box_s, validw);
    }
    nms_mask<<<PRE, 128, 0, stream>>>(box_s, maskb);
    nms_scan_out<<<1, 256, 0, stream>>>(maskb, validw, box_s, out + (size_t)NANCH * 5);
}

// Round 10
// 1090.792 us; speedup vs baseline: 1.0994x; 1.0994x over previous
//
#include <hip/hip_runtime.h>
#include <hip/hip_fp16.h>
#include <stdint.h>

#define HH 100
#define WW 100
#define NPIX 10000
#define CIN 1024
#define COUT 1024
#define NA 9
#define NANCH 90000
#define PRE 6000
#define POST 300
#define SORTN 131072
#define MASKW 96
#define NW 94
#define K9 9216          // CIN*9
#define SPAD 10404       // 102*102 padded pixel rows
#define WSCALE 1024.0f   // exact pow2 pre-scale for w split (avoids fp16 subnormals)
#define KH 48            // padded head output count (9 cls + 36 box + 3 pad)

// conv tiling: 256co x 160px, 512 thr (8 waves, 2/SIMD), 3 LDS buffers,
// counted-vmcnt 2-step-lookahead pipeline (T3/T4). R8 structure (455us) +
// isolated T5 setprio around the MFMA cluster.
#define PXT 160
#define BUFB 53248       // A1@0(16K) A2@16384(16K) B1@32768(10K) B2@43008(10K)
#define NSTEP 288        // 9 taps x 32 ci-steps

#define HEADB 157        // rpn_head real blocks = (NPIX+63)/64

typedef unsigned short u16;
typedef _Float16 f16x8 __attribute__((ext_vector_type(8)));
typedef float f32x4 __attribute__((ext_vector_type(4)));

__device__ __forceinline__ void gload16(const u16* g, char* l)
{
    __builtin_amdgcn_global_load_lds((const void*)g, (void*)l, 16, 0, 0);
}

// ---------------------------------------------------------------------------
// xsplit (+fused border zeroing)
// ---------------------------------------------------------------------------
__global__ __launch_bounds__(256) void xsplit(
    const float* __restrict__ x, u16* __restrict__ xt1, u16* __restrict__ xt2)
{
    __shared__ unsigned sh[32][257];   // [px_local][ci_local]: h1<<16 | h2
    const int t = threadIdx.x;
    if (blockIdx.x >= 313) {
        int idx = (blockIdx.x - 313) * 4 + blockIdx.y;   // 0..403
        int spx;
        if (idx < 102) spx = idx;
        else if (idx < 204) spx = 10302 + (idx - 102);
        else { int k = idx - 204; spx = (1 + (k >> 1)) * 102 + (k & 1) * 101; }
        size_t o = (size_t)spx * 1024 + t * 4;
        *(ushort4*)&xt1[o] = make_ushort4(0, 0, 0, 0);
        *(ushort4*)&xt2[o] = make_ushort4(0, 0, 0, 0);
        return;
    }
    const int px0 = blockIdx.x * 32;
    const int ci0 = blockIdx.y * 256;
    for (int it = 0; it < 32; ++it) {
        int idx = it * 256 + t;
        int a = idx >> 5, b = idx & 31;
        int p = px0 + b;
        float v = (p < NPIX) ? x[(size_t)(ci0 + a) * NPIX + p] : 0.f;
        __half h1 = __float2half_rn(v);
        __half h2 = __float2half_rn(v - __half2float(h1));
        sh[b][a] = ((unsigned)__half_as_ushort(h1) << 16) | __half_as_ushort(h2);
    }
    __syncthreads();
    for (int it = 0; it < 8; ++it) {
        int u = it * 256 + t;
        int pl = u >> 6, cq = u & 63;
        int p = px0 + pl;
        if (p >= NPIX) continue;
        int r = p / 100, c = p - r * 100;
        int spx = (r + 1) * 102 + (c + 1);
        unsigned w0 = sh[pl][cq * 4 + 0], w1 = sh[pl][cq * 4 + 1];
        unsigned w2 = sh[pl][cq * 4 + 2], w3 = sh[pl][cq * 4 + 3];
        ushort4 v1 = make_ushort4((u16)(w0 >> 16), (u16)(w1 >> 16), (u16)(w2 >> 16), (u16)(w3 >> 16));
        ushort4 v2 = make_ushort4((u16)(w0 & 0xffff), (u16)(w1 & 0xffff), (u16)(w2 & 0xffff), (u16)(w3 & 0xffff));
        size_t o = (size_t)spx * 1024 + ci0 + cq * 4;
        *(ushort4*)&xt1[o] = v1;
        *(ushort4*)&xt2[o] = v2;
    }
}

// ---------------------------------------------------------------------------
// wsplit (+fused wh_prep)
// ---------------------------------------------------------------------------
__global__ __launch_bounds__(256) void wsplit(
    const float* __restrict__ w1, u16* __restrict__ wp1, u16* __restrict__ wp2,
    const float* __restrict__ wcls, const float* __restrict__ wbox,
    float* __restrict__ wh)
{
    __shared__ float sw[K9];
    const int t = threadIdx.x;
    if (blockIdx.x >= COUT) {
        int e = (blockIdx.x - COUT) * 256 + t;     // over CIN*KH
        if (e < CIN * KH) {
            int c = e / KH, k = e - c * KH;
            float v = 0.f;
            if (k < 9) v = wcls[k * CIN + c];
            else if (k < 45) v = wbox[(k - 9) * CIN + c];
            wh[e] = v;
        }
        return;
    }
    const int co = blockIdx.x;
    for (int it = 0; it < 36; ++it)
        sw[it * 256 + t] = w1[(size_t)co * K9 + it * 256 + t];
    __syncthreads();
    for (int tap = 0; tap < 9; ++tap) {
        for (int it = 0; it < 4; ++it) {
            int ci = it * 256 + t;
            float v = sw[ci * 9 + tap] * WSCALE;
            __half h1 = __float2half_rn(v);
            __half h2 = __float2half_rn(v - __half2float(h1));
            size_t o = (size_t)tap * (COUT * 1024) + (size_t)co * 1024 + ci;
            wp1[o] = __half_as_ushort(h1);
            wp2[o] = __half_as_ushort(h2);
        }
    }
}

// ---------------------------------------------------------------------------
// conv_mfma: 3x3 conv via fp16-split MFMA. Block 256co x 160px, 512 thr,
// wave tile 64x80, 8 waves. 3-buffer LDS, 2-step lookahead, counted
// s_waitcnt vmcnt(6) (never 0 in steady state) + raw s_barrier.
// R8 rotating-index loop (455us) + T5 setprio around the MFMA cluster
// (the ONLY delta vs R8 — isolating R9's bundled regression).
// ---------------------------------------------------------------------------
__global__ __launch_bounds__(512, 1) void conv_mfma(
    const u16* __restrict__ xt1, const u16* __restrict__ xt2,
    const u16* __restrict__ wp1, const u16* __restrict__ wp2,
    const float* __restrict__ b1, float* __restrict__ y)
{
    __shared__ __align__(16) char lds[3 * BUFB];   // 156 KiB
    const int t = threadIdx.x;
    const int co0 = blockIdx.x * 256;
    const int px0 = blockIdx.y * PXT;
    const int lane = t & 63;
    const int wv = __builtin_amdgcn_readfirstlane(t >> 6);   // 0..7
    const int wm = (wv >> 1) * 64;          // co sub-tile: 0,64,128,192
    const int wn = (wv & 1) * 80;           // px sub-tile: 0,80

    const int qs = (lane & 3) ^ ((lane >> 3) & 3);

    // A: wave wv stages co rows [wv*32, wv*32+32) for both planes (4 issues)
    const int ar0 = wv * 32, ar1 = wv * 32 + 16;
    const size_t aOff0 = (size_t)(co0 + ar0 + (lane >> 2)) * 1024 + qs * 8;
    const size_t aOff1 = (size_t)(co0 + ar1 + (lane >> 2)) * 1024 + qs * 8;

    // B: unit u covers rows [u*16,u*16+16); wave wv takes u=wv and (wv<2) 8+wv
    const int nbu = (wv < 2) ? 2 : 1;
    size_t bOff[2]; int bLds[2];
#pragma unroll
    for (int s = 0; s < 2; ++s) {
        int r0 = (wv + 8 * s) * 16;
        if (r0 >= PXT) r0 = 0;                    // unused slot
        int p = px0 + r0 + (lane >> 2);
        if (p > NPIX - 1) p = NPIX - 1;
        int rr = p / 100, cc = p - rr * 100;
        bOff[s] = (size_t)((rr + 1) * 102 + cc + 1) * 1024 + qs * 8;
        bLds[s] = r0 * 64;
    }

    const int qf = ((lane >> 4) ^ (((lane & 15) >> 1) & 3)) * 16;
    const int fA = (wm + (lane & 15)) * 64 + qf;
    const int fB = 32768 + (wn + (lane & 15)) * 64 + qf;

    f32x4 acc[4][5] = {};

    auto STAGE = [&](int buf, int step) {
        char* lb = lds + buf * BUFB;
        const int tap = step >> 5;
        const int ci0 = (step & 31) << 5;
        const int dy = (tap * 11) >> 5;            // tap/3 for 0..8
        const int tsh = (dy - 1) * 102 + (tap - dy * 3) - 1;
        const size_t adelta = (size_t)tap * 1048576 + ci0;
        const ptrdiff_t bdelta = (ptrdiff_t)tsh * 1024 + ci0;
        gload16(wp1 + aOff0 + adelta, lb + ar0 * 64);
        gload16(wp1 + aOff1 + adelta, lb + ar1 * 64);
        gload16(wp2 + aOff0 + adelta, lb + 16384 + ar0 * 64);
        gload16(wp2 + aOff1 + adelta, lb + 16384 + ar1 * 64);
#pragma unroll
        for (int s = 0; s < 2; ++s) {
            if (s < nbu) {
                gload16(xt1 + (ptrdiff_t)bOff[s] + bdelta, lb + 32768 + bLds[s]);
                gload16(xt2 + (ptrdiff_t)bOff[s] + bdelta, lb + 43008 + bLds[s]);
            }
        }
    };

    auto COMPUTE = [&](int buf) {
        const char* lb = lds + buf * BUFB;
        f16x8 A1[4], A2[4], B1[5], B2[5];
#pragma unroll
        for (int mi = 0; mi < 4; ++mi) {
            A1[mi] = *(const f16x8*)(lb + fA + mi * 1024);
            A2[mi] = *(const f16x8*)(lb + 16384 + fA + mi * 1024);
        }
#pragma unroll
        for (int ni = 0; ni < 5; ++ni) {
            B1[ni] = *(const f16x8*)(lb + fB + ni * 1024);
            B2[ni] = *(const f16x8*)(lb + fB + 10240 + ni * 1024);
        }
#pragma unroll
        for (int mi = 0; mi < 4; ++mi)
#pragma unroll
            for (int ni = 0; ni < 5; ++ni) {
                acc[mi][ni] = __builtin_amdgcn_mfma_f32_16x16x32_f16(A1[mi], B1[ni], acc[mi][ni], 0, 0, 0);
                acc[mi][ni] = __builtin_amdgcn_mfma_f32_16x16x32_f16(A1[mi], B2[ni], acc[mi][ni], 0, 0, 0);
                acc[mi][ni] = __builtin_amdgcn_mfma_f32_16x16x32_f16(A2[mi], B1[ni], acc[mi][ni], 0, 0, 0);
            }
    };

    // prologue: 2 stages in flight; vmcnt(6) <= min per-stage issues (6), so
    // stage0's loads are fully retired before the barrier.
    STAGE(0, 0);
    STAGE(1, 1);
    asm volatile("s_waitcnt vmcnt(6)" ::: "memory");
    __builtin_amdgcn_s_barrier();

    int cb = 0;
    for (int k = 0; k < NSTEP; ++k) {
        int sb = cb + 2; if (sb >= 3) sb -= 3;
        if (k + 2 < NSTEP) STAGE(sb, k + 2);   // issue 2 steps ahead
        __builtin_amdgcn_s_setprio(1);
        COMPUTE(cb);                            // loads fly under MFMA
        __builtin_amdgcn_s_setprio(0);
        if (k >= NSTEP - 2) {
            asm volatile("s_waitcnt vmcnt(0)" ::: "memory");   // epilogue drain
        } else {
            asm volatile("s_waitcnt vmcnt(6)" ::: "memory");   // counted wait
        }
        __builtin_amdgcn_s_barrier();
        if (++cb == 3) cb = 0;
    }

    // epilogue: D row=(lane>>4)*4+reg (co), col=lane&15 (px); descale+bias+relu
    const int q4 = (lane >> 4) * 4, nl = lane & 15;
    const float inv = 1.0f / WSCALE;
#pragma unroll
    for (int mi = 0; mi < 4; ++mi) {
        const int cob = co0 + wm + mi * 16 + q4;
        const float bb0 = b1[cob + 0], bb1 = b1[cob + 1];
        const float bb2 = b1[cob + 2], bb3 = b1[cob + 3];
#pragma unroll
        for (int ni = 0; ni < 5; ++ni) {
            const int px = px0 + wn + ni * 16 + nl;
            if (px < NPIX) {
                y[(size_t)(cob + 0) * NPIX + px] = fmaxf(acc[mi][ni][0] * inv + bb0, 0.f);
                y[(size_t)(cob + 1) * NPIX + px] = fmaxf(acc[mi][ni][1] * inv + bb1, 0.f);
                y[(size_t)(cob + 2) * NPIX + px] = fmaxf(acc[mi][ni][2] * inv + bb2, 0.f);
                y[(size_t)(cob + 3) * NPIX + px] = fmaxf(acc[mi][ni][3] * inv + bb3, 0.f);
            }
        }
    }
}

// ---------------------------------------------------------------------------
// rpn_head (pixel-major, +fused key padding)
// ---------------------------------------------------------------------------
__global__ __launch_bounds__(256) void rpn_head(
    const float* __restrict__ y, const float* __restrict__ wh,
    const float* __restrict__ bcls, const float* __restrict__ bbox,
    const float* __restrict__ am, const int* __restrict__ ishape,
    float* __restrict__ out_scores, float* __restrict__ out_deltas,
    float4* __restrict__ boxes, unsigned long long* __restrict__ keys)
{
    __shared__ float red[4][64][KH + 1];
    const int t = threadIdx.x;
    if (blockIdx.x >= HEADB) {
        int i = NANCH + (blockIdx.x - HEADB) * 256 + t;
        if (i < SORTN) keys[i] = 0ull;
        return;
    }
    const int lane = t & 63;
    const int q = __builtin_amdgcn_readfirstlane(t >> 6);
    const int p = blockIdx.x * 64 + lane;
    const int pp = (p < NPIX) ? p : (NPIX - 1);

    float acc[45];
#pragma unroll
    for (int k = 0; k < 45; ++k) acc[k] = 0.f;

    const float* __restrict__ yq  = y  + (size_t)q * 256 * NPIX + pp;
    const float* __restrict__ whq = wh + (size_t)q * 256 * KH;
    for (int c = 0; c < 256; ++c) {
        float yv = yq[(size_t)c * NPIX];
        const float* wr = whq + c * KH;
#pragma unroll
        for (int k = 0; k < 45; ++k) acc[k] += yv * wr[k];
    }

#pragma unroll
    for (int k = 0; k < 45; ++k) red[q][lane][k] = acc[k];
    __syncthreads();

    if (t >= 64 || p >= NPIX) return;

    float s[45];
#pragma unroll
    for (int k = 0; k < 45; ++k)
        s[k] = (red[0][lane][k] + red[1][lane][k]) + (red[2][lane][k] + red[3][lane][k]);

    const float imh = (float)ishape[1], imw = (float)ishape[2];
#pragma unroll
    for (int a = 0; a < 9; ++a) {
        const int i = p * NA + a;
        float logit = s[a] + bcls[a];
        float score = 1.f / (1.f + expf(-logit));
        float d0 = s[9 + a * 4 + 0] + bbox[a * 4 + 0];
        float d1 = s[9 + a * 4 + 1] + bbox[a * 4 + 1];
        float d2 = s[9 + a * 4 + 2] + bbox[a * 4 + 2];
        float d3 = s[9 + a * 4 + 3] + bbox[a * 4 + 3];
        out_scores[i] = score;
        out_deltas[i * 4 + 0] = d0;
        out_deltas[i * 4 + 1] = d1;
        out_deltas[i * 4 + 2] = d2;
        out_deltas[i * 4 + 3] = d3;

        float cy = am[i * 4 + 0], cx = am[i * 4 + 1];
        float ah = am[i * 4 + 2], aw = am[i * 4 + 3];
        float ctry = cy + d0 * ah, ctrx = cx + d1 * aw;
        float hh = ah * expf(d2), ww = aw * expf(d3);
        float y1 = fmaxf(ctry - 0.5f * hh, 0.f);
        float x1 = fmaxf(ctrx - 0.5f * ww, 0.f);
        float y2 = fminf(ctry + 0.5f * hh, imh);
        float x2 = fminf(ctrx + 0.5f * ww, imw);
        boxes[i] = make_float4(y1, x1, y2, x2);
        unsigned sb = __float_as_uint(score);
        keys[i] = ((unsigned long long)sb << 32) | (unsigned)i;
    }
}

// ---------------------------------------------------------------------------
// Bitonic sort (descending) of SORTN u64 keys — 8192-element blocks (64KB LDS,
// 1024 thr). local8k covers L<=8192; lmerge8k covers d<=4096; gpass for
// d>=8192. Final lmerge8k block 0 fuses the top-PRE gather. Windows 11..15
// (keys >= 90112) are all-zero => already sorted; local8k launches 11 blocks.
// ---------------------------------------------------------------------------
__global__ __launch_bounds__(1024) void bitonic_local8k(unsigned long long* keys)
{
    __shared__ unsigned long long s[8192];
    const int base = blockIdx.x * 8192, t = threadIdx.x;
    for (int k = t; k < 8192; k += 1024) s[k] = keys[base + k];
    for (int L = 2; L <= 8192; L <<= 1) {
        for (int d = L >> 1; d >= 1; d >>= 1) {
            __syncthreads();
            for (int pr = t; pr < 4096; pr += 1024) {
                int i = ((pr & ~(d - 1)) << 1) | (pr & (d - 1));
                int j = i + d;
                bool desc = (((base + i) & L) == 0);
                unsigned long long va = s[i], vb = s[j];
                bool sw = desc ? (va < vb) : (va > vb);
                if (sw) { s[i] = vb; s[j] = va; }
            }
        }
    }
    __syncthreads();
    for (int k = t; k < 8192; k += 1024) keys[base + k] = s[k];
}

__global__ __launch_bounds__(256) void bitonic_gpass(unsigned long long* keys, int L, int d)
{
    int pr = blockIdx.x * 256 + threadIdx.x;
    int i = ((pr & ~(d - 1)) << 1) | (pr & (d - 1));
    int j = i + d;
    bool desc = ((i & L) == 0);
    unsigned long long va = keys[i], vb = keys[j];
    bool sw = desc ? (va < vb) : (va > vb);
    if (sw) { keys[i] = vb; keys[j] = va; }
}

__global__ __launch_bounds__(1024) void bitonic_lmerge8k(
    unsigned long long* keys, int L,
    const float4* __restrict__ boxes, float4* __restrict__ box_s,
    unsigned long long* __restrict__ validw)
{
    __shared__ unsigned long long s[8192];
    const int base = blockIdx.x * 8192, t = threadIdx.x;
    for (int k = t; k < 8192; k += 1024) s[k] = keys[base + k];
    const bool desc = ((base & L) == 0);
    for (int d = 4096; d >= 1; d >>= 1) {
        __syncthreads();
        for (int pr = t; pr < 4096; pr += 1024) {
            int i = ((pr & ~(d - 1)) << 1) | (pr & (d - 1));
            int j = i + d;
            unsigned long long va = s[i], vb = s[j];
            bool sw = desc ? (va < vb) : (va > vb);
            if (sw) { s[i] = vb; s[j] = va; }
        }
    }
    __syncthreads();
    for (int k = t; k < 8192; k += 1024) keys[base + k] = s[k];
    // final merge, block 0: s[0..8191] is the global top-8192 (descending) —
    // fused gather of the top-PRE boxes + min-size valid ballot.
    if (L == SORTN && blockIdx.x == 0) {
        for (int k = t; k < 6144; k += 1024) {
            bool valid = false;
            if (k < PRE) {
                unsigned idx = (unsigned)(s[k] & 0xffffffffull);
                float4 b = boxes[idx];
                box_s[k] = b;
                valid = ((b.z - b.x) >= 16.f) && ((b.w - b.y) >= 16.f);
            }
            unsigned long long bal = __ballot(valid);
            if ((t & 63) == 0) validw[k >> 6] = bal;
        }
    }
}

// ---------------------------------------------------------------------------
__global__ __launch_bounds__(128) void nms_mask(
    const float4* __restrict__ box_s, unsigned long long* __restrict__ mask)
{
    const int i = blockIdx.x;
    const int w = threadIdx.x;
    if (w >= NW) return;
    float4 bi = box_s[i];
    float areai = (bi.z - bi.x) * (bi.w - bi.y);
    unsigned long long m = 0ull;
    const int j0 = w * 64;
    if (j0 + 63 > i) {
#pragma unroll 4
        for (int b = 0; b < 64; ++b) {
            int j = j0 + b;
            if (j <= i || j >= PRE) continue;
            float4 bj = box_s[j];
            float areaj = (bj.z - bj.x) * (bj.w - bj.y);
            float iy1 = fmaxf(bi.x, bj.x), ix1 = fmaxf(bi.y, bj.y);
            float iy2 = fminf(bi.z, bj.z), ix2 = fminf(bi.w, bj.w);
            float inter = fmaxf(iy2 - iy1, 0.f) * fmaxf(ix2 - ix1, 0.f);
            float iou = inter / (areai + areaj - inter + 1e-8f);
            if (iou > 0.7f) m |= (1ull << b);
        }
    }
    mask[(size_t)i * MASKW + w] = m;
}

// ---------------------------------------------------------------------------
// nms_scan (+fused out_gather)
// ---------------------------------------------------------------------------
__global__ __launch_bounds__(256) void nms_scan_out(
    const unsigned long long* __restrict__ mask,
    const unsigned long long* __restrict__ validw,
    const float4* __restrict__ box_s, float* __restrict__ outp)
{
    __shared__ unsigned long long kw_s[NW];
    __shared__ int prefix[NW];
    const int t = threadIdx.x;
    if (t < 64) {
        const int l = t;
        unsigned long long r0 = ~validw[l];
        unsigned long long r1 = (l < NW - 64) ? ~validw[64 + l] : ~0ull;
        unsigned long long p0[16], p1[16];
#pragma unroll
        for (int k = 0; k < 16; ++k) {
            p0[k] = mask[(size_t)k * MASKW + l];
            p1[k] = (l < NW - 64) ? mask[(size_t)k * MASKW + 64 + l] : 0ull;
        }
        int kept = 0;
        for (int w = 0; w < NW && kept < POST; ++w) {
            unsigned long long Wc = (w < 64) ? __shfl(r0, w) : __shfl(r1, w - 64);
#pragma unroll 16
            for (int b = 0; b < 64; ++b) {
                int i = w * 64 + b;
                if (i >= PRE) break;
                int slot = i & 15;
                unsigned long long m0 = p0[slot], m1 = p1[slot];
                int nxt = i + 16;
                if (nxt < PRE) {
                    p0[slot] = mask[(size_t)nxt * MASKW + l];
                    p1[slot] = (l < NW - 64) ? mask[(size_t)nxt * MASKW + 64 + l] : 0ull;
                }
                if (!((Wc >> b) & 1ull)) {
                    r0 |= m0; r1 |= m1;
                    Wc = (w < 64) ? __shfl(r0, w) : __shfl(r1, w - 64);
                    ++kept;
                }
            }
        }
        kw_s[l] = ~r0;
        if (l < NW - 64) kw_s[64 + l] = ~r1;
    }
    __syncthreads();
    if (t == 0) {
        int cum = 0;
        for (int w = 0; w < NW; ++w) { prefix[w] = cum; cum += __popcll(kw_s[w]); }
    }
    for (int k = t; k < POST * 4; k += 256) outp[k] = 0.f;
    __syncthreads();
    for (int i = t; i < PRE; i += 256) {
        int w = i >> 6, b = i & 63;
        unsigned long long kw = kw_s[w];
        if ((kw >> b) & 1ull) {
            int rank = prefix[w] + __popcll(kw & ((1ull << b) - 1ull));
            if (rank < POST) {
                float4 bx = box_s[i];
                outp[rank * 4 + 0] = bx.x;
                outp[rank * 4 + 1] = bx.y;
                outp[rank * 4 + 2] = bx.z;
                outp[rank * 4 + 3] = bx.w;
            }
        }
    }
}

// ---------------------------------------------------------------------------
extern "C" void kernel_launch(void* const* d_in, const int* in_sizes, int n_in,
                              void* d_out, int out_size, void* d_ws, size_t ws_size,
                              hipStream_t stream)
{
    const float* x      = (const float*)d_in[0];
    const int*   ishape = (const int*)  d_in[1];
    const float* am     = (const float*)d_in[2];
    const float* w1   = (const float*)d_in[6];
    const float* b1   = (const float*)d_in[7];
    const float* wcls = (const float*)d_in[8];
    const float* bcls = (const float*)d_in[9];
    const float* wbox = (const float*)d_in[10];
    const float* bbox = (const float*)d_in[11];
    float* out = (float*)d_out;

    char* ws = (char*)d_ws;
    size_t off = 0;
    float* y  = (float*)(ws + off);  off += (size_t)COUT * NPIX * 4;
    u16* xt1  = (u16*)(ws + off);    off += (size_t)SPAD * 1024 * 2;
    u16* xt2  = (u16*)(ws + off);    off += (size_t)SPAD * 1024 * 2;
    u16* wp1  = (u16*)(ws + off);    off += (size_t)9 * COUT * 1024 * 2;
    u16* wp2  = (u16*)(ws + off);    off += (size_t)9 * COUT * 1024 * 2;
    float4* boxes = (float4*)(ws + off);              off += (size_t)NANCH * 16;
    unsigned long long* keys = (unsigned long long*)(ws + off); off += (size_t)SORTN * 8;
    float4* box_s = (float4*)(ws + off);              off += (size_t)PRE * 16;
    unsigned long long* validw = (unsigned long long*)(ws + off); off += 96 * 8;
    unsigned long long* maskb  = (unsigned long long*)(ws + off); off += (size_t)PRE * MASKW * 8;
    float* wh = (float*)(ws + off);  off += (size_t)CIN * KH * 4;

    xsplit<<<dim3(414, 4), 256, 0, stream>>>(x, xt1, xt2);
    wsplit<<<COUT + (CIN * KH + 255) / 256, 256, 0, stream>>>(w1, wp1, wp2, wcls, wbox, wh);
    conv_mfma<<<dim3(4, (NPIX + PXT - 1) / PXT), 512, 0, stream>>>(xt1, xt2, wp1, wp2, b1, y);
    rpn_head<<<HEADB + (SORTN - NANCH + 255) / 256, 256, 0, stream>>>(
        y, wh, bcls, bbox, am, ishape, out, out + NANCH, boxes, keys);
    bitonic_local8k<<<11, 1024, 0, stream>>>(keys);   // windows 11..15 all-zero
    for (int L = 16384; L <= SORTN; L <<= 1) {
        for (int d = L >> 1; d >= 8192; d >>= 1)
            bitonic_gpass<<<SORTN / 512, 256, 0, stream>>>(keys, L, d);
        bitonic_lmerge8k<<<SORTN / 8192, 1024, 0, stream>>>(keys, L, boxes, box_s, validw);
    }
    nms_mask<<<PRE, 128, 0, stream>>>(box_s, maskb);
    nms_scan_out<<<1, 256, 0, stream>>>(maskb, validw, box_s, out + (size_t)NANCH * 5);
}

// Round 11
// 1087.867 us; speedup vs baseline: 1.1024x; 1.0027x over previous
//
#include <hip/hip_runtime.h>
#include <hip/hip_fp16.h>
#include <stdint.h>

#define HH 100
#define WW 100
#define NPIX 10000
#define CIN 1024
#define COUT 1024
#define NA 9
#define NANCH 90000
#define PRE 6000
#define POST 300
#define SORTN 131072
#define MASKW 96
#define NW 94
#define K9 9216          // CIN*9
#define SPAD 10404       // 102*102 padded pixel rows
#define WSCALE 1024.0f   // exact pow2 pre-scale for w split (avoids fp16 subnormals)
#define KH 48            // padded head output count (9 cls + 36 box + 3 pad)

// conv tiling: 256co x 160px, 512 thr (8 waves, 2/SIMD), 3 LDS buffers,
// counted-vmcnt 2-step-lookahead pipeline (T3/T4). R8 configuration —
// best measured (conv 455us, total 1076us). setprio removed (R10: null).
#define PXT 160
#define BUFB 53248       // A1@0(16K) A2@16384(16K) B1@32768(10K) B2@43008(10K)
#define NSTEP 288        // 9 taps x 32 ci-steps

#define HEADB 157        // rpn_head real blocks = (NPIX+63)/64

typedef unsigned short u16;
typedef _Float16 f16x8 __attribute__((ext_vector_type(8)));
typedef float f32x4 __attribute__((ext_vector_type(4)));

__device__ __forceinline__ void gload16(const u16* g, char* l)
{
    __builtin_amdgcn_global_load_lds((const void*)g, (void*)l, 16, 0, 0);
}

// ---------------------------------------------------------------------------
// xsplit (+fused border zeroing)
// ---------------------------------------------------------------------------
__global__ __launch_bounds__(256) void xsplit(
    const float* __restrict__ x, u16* __restrict__ xt1, u16* __restrict__ xt2)
{
    __shared__ unsigned sh[32][257];   // [px_local][ci_local]: h1<<16 | h2
    const int t = threadIdx.x;
    if (blockIdx.x >= 313) {
        int idx = (blockIdx.x - 313) * 4 + blockIdx.y;   // 0..403
        int spx;
        if (idx < 102) spx = idx;
        else if (idx < 204) spx = 10302 + (idx - 102);
        else { int k = idx - 204; spx = (1 + (k >> 1)) * 102 + (k & 1) * 101; }
        size_t o = (size_t)spx * 1024 + t * 4;
        *(ushort4*)&xt1[o] = make_ushort4(0, 0, 0, 0);
        *(ushort4*)&xt2[o] = make_ushort4(0, 0, 0, 0);
        return;
    }
    const int px0 = blockIdx.x * 32;
    const int ci0 = blockIdx.y * 256;
    for (int it = 0; it < 32; ++it) {
        int idx = it * 256 + t;
        int a = idx >> 5, b = idx & 31;
        int p = px0 + b;
        float v = (p < NPIX) ? x[(size_t)(ci0 + a) * NPIX + p] : 0.f;
        __half h1 = __float2half_rn(v);
        __half h2 = __float2half_rn(v - __half2float(h1));
        sh[b][a] = ((unsigned)__half_as_ushort(h1) << 16) | __half_as_ushort(h2);
    }
    __syncthreads();
    for (int it = 0; it < 8; ++it) {
        int u = it * 256 + t;
        int pl = u >> 6, cq = u & 63;
        int p = px0 + pl;
        if (p >= NPIX) continue;
        int r = p / 100, c = p - r * 100;
        int spx = (r + 1) * 102 + (c + 1);
        unsigned w0 = sh[pl][cq * 4 + 0], w1 = sh[pl][cq * 4 + 1];
        unsigned w2 = sh[pl][cq * 4 + 2], w3 = sh[pl][cq * 4 + 3];
        ushort4 v1 = make_ushort4((u16)(w0 >> 16), (u16)(w1 >> 16), (u16)(w2 >> 16), (u16)(w3 >> 16));
        ushort4 v2 = make_ushort4((u16)(w0 & 0xffff), (u16)(w1 & 0xffff), (u16)(w2 & 0xffff), (u16)(w3 & 0xffff));
        size_t o = (size_t)spx * 1024 + ci0 + cq * 4;
        *(ushort4*)&xt1[o] = v1;
        *(ushort4*)&xt2[o] = v2;
    }
}

// ---------------------------------------------------------------------------
// wsplit (+fused wh_prep)
// ---------------------------------------------------------------------------
__global__ __launch_bounds__(256) void wsplit(
    const float* __restrict__ w1, u16* __restrict__ wp1, u16* __restrict__ wp2,
    const float* __restrict__ wcls, const float* __restrict__ wbox,
    float* __restrict__ wh)
{
    __shared__ float sw[K9];
    const int t = threadIdx.x;
    if (blockIdx.x >= COUT) {
        int e = (blockIdx.x - COUT) * 256 + t;     // over CIN*KH
        if (e < CIN * KH) {
            int c = e / KH, k = e - c * KH;
            float v = 0.f;
            if (k < 9) v = wcls[k * CIN + c];
            else if (k < 45) v = wbox[(k - 9) * CIN + c];
            wh[e] = v;
        }
        return;
    }
    const int co = blockIdx.x;
    for (int it = 0; it < 36; ++it)
        sw[it * 256 + t] = w1[(size_t)co * K9 + it * 256 + t];
    __syncthreads();
    for (int tap = 0; tap < 9; ++tap) {
        for (int it = 0; it < 4; ++it) {
            int ci = it * 256 + t;
            float v = sw[ci * 9 + tap] * WSCALE;
            __half h1 = __float2half_rn(v);
            __half h2 = __float2half_rn(v - __half2float(h1));
            size_t o = (size_t)tap * (COUT * 1024) + (size_t)co * 1024 + ci;
            wp1[o] = __half_as_ushort(h1);
            wp2[o] = __half_as_ushort(h2);
        }
    }
}

// ---------------------------------------------------------------------------
// conv_mfma: 3x3 conv via fp16-split MFMA. Block 256co x 160px, 512 thr,
// wave tile 64x80 (m4 x n5), 8 waves (4co x 2px). K = 9 taps x 1024 ci,
// kstep 32. 3-buffer LDS, 2-step lookahead, counted s_waitcnt vmcnt(6)
// (never 0 in steady state) + raw s_barrier: load latency spans 2 full
// compute steps instead of being drained every step.
// Per-wave stage issues: 4 A + {4,2} B = 8 (wv<2) or 6 (wv>=2); waiting
// vmcnt(6) always fully drains the previous stage (6<=min issues).
// Swizzle: q-XOR involution on global source + ds_read (row bases 16-aligned).
// ---------------------------------------------------------------------------
__global__ __launch_bounds__(512, 1) void conv_mfma(
    const u16* __restrict__ xt1, const u16* __restrict__ xt2,
    const u16* __restrict__ wp1, const u16* __restrict__ wp2,
    const float* __restrict__ b1, float* __restrict__ y)
{
    __shared__ __align__(16) char lds[3 * BUFB];   // 156 KiB
    const int t = threadIdx.x;
    const int co0 = blockIdx.x * 256;
    const int px0 = blockIdx.y * PXT;
    const int lane = t & 63;
    const int wv = __builtin_amdgcn_readfirstlane(t >> 6);   // 0..7
    const int wm = (wv >> 1) * 64;          // co sub-tile: 0,64,128,192
    const int wn = (wv & 1) * 80;           // px sub-tile: 0,80

    const int qs = (lane & 3) ^ ((lane >> 3) & 3);

    // A: wave wv stages co rows [wv*32, wv*32+32) for both planes (4 issues)
    const int ar0 = wv * 32, ar1 = wv * 32 + 16;
    const size_t aOff0 = (size_t)(co0 + ar0 + (lane >> 2)) * 1024 + qs * 8;
    const size_t aOff1 = (size_t)(co0 + ar1 + (lane >> 2)) * 1024 + qs * 8;

    // B: unit u covers rows [u*16,u*16+16); wave wv takes u=wv and (wv<2) 8+wv
    const int nbu = (wv < 2) ? 2 : 1;
    size_t bOff[2]; int bLds[2];
#pragma unroll
    for (int s = 0; s < 2; ++s) {
        int r0 = (wv + 8 * s) * 16;
        if (r0 >= PXT) r0 = 0;                    // unused slot
        int p = px0 + r0 + (lane >> 2);
        if (p > NPIX - 1) p = NPIX - 1;
        int rr = p / 100, cc = p - rr * 100;
        bOff[s] = (size_t)((rr + 1) * 102 + cc + 1) * 1024 + qs * 8;
        bLds[s] = r0 * 64;
    }

    const int qf = ((lane >> 4) ^ (((lane & 15) >> 1) & 3)) * 16;
    const int fA = (wm + (lane & 15)) * 64 + qf;
    const int fB = 32768 + (wn + (lane & 15)) * 64 + qf;

    f32x4 acc[4][5] = {};

    auto STAGE = [&](int buf, int step) {
        char* lb = lds + buf * BUFB;
        const int tap = step >> 5;
        const int ci0 = (step & 31) << 5;
        const int dy = (tap * 11) >> 5;            // tap/3 for 0..8
        const int tsh = (dy - 1) * 102 + (tap - dy * 3) - 1;
        const size_t adelta = (size_t)tap * 1048576 + ci0;
        const ptrdiff_t bdelta = (ptrdiff_t)tsh * 1024 + ci0;
        gload16(wp1 + aOff0 + adelta, lb + ar0 * 64);
        gload16(wp1 + aOff1 + adelta, lb + ar1 * 64);
        gload16(wp2 + aOff0 + adelta, lb + 16384 + ar0 * 64);
        gload16(wp2 + aOff1 + adelta, lb + 16384 + ar1 * 64);
#pragma unroll
        for (int s = 0; s < 2; ++s) {
            if (s < nbu) {
                gload16(xt1 + (ptrdiff_t)bOff[s] + bdelta, lb + 32768 + bLds[s]);
                gload16(xt2 + (ptrdiff_t)bOff[s] + bdelta, lb + 43008 + bLds[s]);
            }
        }
    };

    auto COMPUTE = [&](int buf) {
        const char* lb = lds + buf * BUFB;
        f16x8 A1[4], A2[4], B1[5], B2[5];
#pragma unroll
        for (int mi = 0; mi < 4; ++mi) {
            A1[mi] = *(const f16x8*)(lb + fA + mi * 1024);
            A2[mi] = *(const f16x8*)(lb + 16384 + fA + mi * 1024);
        }
#pragma unroll
        for (int ni = 0; ni < 5; ++ni) {
            B1[ni] = *(const f16x8*)(lb + fB + ni * 1024);
            B2[ni] = *(const f16x8*)(lb + fB + 10240 + ni * 1024);
        }
#pragma unroll
        for (int mi = 0; mi < 4; ++mi)
#pragma unroll
            for (int ni = 0; ni < 5; ++ni) {
                acc[mi][ni] = __builtin_amdgcn_mfma_f32_16x16x32_f16(A1[mi], B1[ni], acc[mi][ni], 0, 0, 0);
                acc[mi][ni] = __builtin_amdgcn_mfma_f32_16x16x32_f16(A1[mi], B2[ni], acc[mi][ni], 0, 0, 0);
                acc[mi][ni] = __builtin_amdgcn_mfma_f32_16x16x32_f16(A2[mi], B1[ni], acc[mi][ni], 0, 0, 0);
            }
    };

    // prologue: 2 stages in flight; vmcnt(6) <= min per-stage issues (6), so
    // stage0's loads are fully retired before the barrier.
    STAGE(0, 0);
    STAGE(1, 1);
    asm volatile("s_waitcnt vmcnt(6)" ::: "memory");
    __builtin_amdgcn_s_barrier();

    int cb = 0;
    for (int k = 0; k < NSTEP; ++k) {
        int sb = cb + 2; if (sb >= 3) sb -= 3;
        if (k + 2 < NSTEP) STAGE(sb, k + 2);   // issue 2 steps ahead
        COMPUTE(cb);                            // loads fly under MFMA
        if (k >= NSTEP - 2) {
            asm volatile("s_waitcnt vmcnt(0)" ::: "memory");   // epilogue drain
        } else {
            asm volatile("s_waitcnt vmcnt(6)" ::: "memory");   // counted wait
        }
        __builtin_amdgcn_s_barrier();
        if (++cb == 3) cb = 0;
    }

    // epilogue: D row=(lane>>4)*4+reg (co), col=lane&15 (px); descale+bias+relu
    const int q4 = (lane >> 4) * 4, nl = lane & 15;
    const float inv = 1.0f / WSCALE;
#pragma unroll
    for (int mi = 0; mi < 4; ++mi) {
        const int cob = co0 + wm + mi * 16 + q4;
        const float bb0 = b1[cob + 0], bb1 = b1[cob + 1];
        const float bb2 = b1[cob + 2], bb3 = b1[cob + 3];
#pragma unroll
        for (int ni = 0; ni < 5; ++ni) {
            const int px = px0 + wn + ni * 16 + nl;
            if (px < NPIX) {
                y[(size_t)(cob + 0) * NPIX + px] = fmaxf(acc[mi][ni][0] * inv + bb0, 0.f);
                y[(size_t)(cob + 1) * NPIX + px] = fmaxf(acc[mi][ni][1] * inv + bb1, 0.f);
                y[(size_t)(cob + 2) * NPIX + px] = fmaxf(acc[mi][ni][2] * inv + bb2, 0.f);
                y[(size_t)(cob + 3) * NPIX + px] = fmaxf(acc[mi][ni][3] * inv + bb3, 0.f);
            }
        }
    }
}

// ---------------------------------------------------------------------------
// rpn_head (pixel-major, +fused key padding)
// ---------------------------------------------------------------------------
__global__ __launch_bounds__(256) void rpn_head(
    const float* __restrict__ y, const float* __restrict__ wh,
    const float* __restrict__ bcls, const float* __restrict__ bbox,
    const float* __restrict__ am, const int* __restrict__ ishape,
    float* __restrict__ out_scores, float* __restrict__ out_deltas,
    float4* __restrict__ boxes, unsigned long long* __restrict__ keys)
{
    __shared__ float red[4][64][KH + 1];
    const int t = threadIdx.x;
    if (blockIdx.x >= HEADB) {
        int i = NANCH + (blockIdx.x - HEADB) * 256 + t;
        if (i < SORTN) keys[i] = 0ull;
        return;
    }
    const int lane = t & 63;
    const int q = __builtin_amdgcn_readfirstlane(t >> 6);
    const int p = blockIdx.x * 64 + lane;
    const int pp = (p < NPIX) ? p : (NPIX - 1);

    float acc[45];
#pragma unroll
    for (int k = 0; k < 45; ++k) acc[k] = 0.f;

    const float* __restrict__ yq  = y  + (size_t)q * 256 * NPIX + pp;
    const float* __restrict__ whq = wh + (size_t)q * 256 * KH;
    for (int c = 0; c < 256; ++c) {
        float yv = yq[(size_t)c * NPIX];
        const float* wr = whq + c * KH;
#pragma unroll
        for (int k = 0; k < 45; ++k) acc[k] += yv * wr[k];
    }

#pragma unroll
    for (int k = 0; k < 45; ++k) red[q][lane][k] = acc[k];
    __syncthreads();

    if (t >= 64 || p >= NPIX) return;

    float s[45];
#pragma unroll
    for (int k = 0; k < 45; ++k)
        s[k] = (red[0][lane][k] + red[1][lane][k]) + (red[2][lane][k] + red[3][lane][k]);

    const float imh = (float)ishape[1], imw = (float)ishape[2];
#pragma unroll
    for (int a = 0; a < 9; ++a) {
        const int i = p * NA + a;
        float logit = s[a] + bcls[a];
        float score = 1.f / (1.f + expf(-logit));
        float d0 = s[9 + a * 4 + 0] + bbox[a * 4 + 0];
        float d1 = s[9 + a * 4 + 1] + bbox[a * 4 + 1];
        float d2 = s[9 + a * 4 + 2] + bbox[a * 4 + 2];
        float d3 = s[9 + a * 4 + 3] + bbox[a * 4 + 3];
        out_scores[i] = score;
        out_deltas[i * 4 + 0] = d0;
        out_deltas[i * 4 + 1] = d1;
        out_deltas[i * 4 + 2] = d2;
        out_deltas[i * 4 + 3] = d3;

        float cy = am[i * 4 + 0], cx = am[i * 4 + 1];
        float ah = am[i * 4 + 2], aw = am[i * 4 + 3];
        float ctry = cy + d0 * ah, ctrx = cx + d1 * aw;
        float hh = ah * expf(d2), ww = aw * expf(d3);
        float y1 = fmaxf(ctry - 0.5f * hh, 0.f);
        float x1 = fmaxf(ctrx - 0.5f * ww, 0.f);
        float y2 = fminf(ctry + 0.5f * hh, imh);
        float x2 = fminf(ctrx + 0.5f * ww, imw);
        boxes[i] = make_float4(y1, x1, y2, x2);
        unsigned sb = __float_as_uint(score);
        keys[i] = ((unsigned long long)sb << 32) | (unsigned)i;
    }
}

// ---------------------------------------------------------------------------
// Bitonic sort (descending) of SORTN u64 keys — 8192-element blocks (64KB LDS,
// 1024 thr). local8k covers L<=8192; lmerge8k covers d<=4096; gpass for
// d>=8192. Final lmerge8k block 0 fuses the top-PRE gather.
// ---------------------------------------------------------------------------
__global__ __launch_bounds__(1024) void bitonic_local8k(unsigned long long* keys)
{
    __shared__ unsigned long long s[8192];
    const int base = blockIdx.x * 8192, t = threadIdx.x;
    for (int k = t; k < 8192; k += 1024) s[k] = keys[base + k];
    for (int L = 2; L <= 8192; L <<= 1) {
        for (int d = L >> 1; d >= 1; d >>= 1) {
            __syncthreads();
            for (int pr = t; pr < 4096; pr += 1024) {
                int i = ((pr & ~(d - 1)) << 1) | (pr & (d - 1));
                int j = i + d;
                bool desc = (((base + i) & L) == 0);
                unsigned long long va = s[i], vb = s[j];
                bool sw = desc ? (va < vb) : (va > vb);
                if (sw) { s[i] = vb; s[j] = va; }
            }
        }
    }
    __syncthreads();
    for (int k = t; k < 8192; k += 1024) keys[base + k] = s[k];
}

__global__ __launch_bounds__(256) void bitonic_gpass(unsigned long long* keys, int L, int d)
{
    int pr = blockIdx.x * 256 + threadIdx.x;
    int i = ((pr & ~(d - 1)) << 1) | (pr & (d - 1));
    int j = i + d;
    bool desc = ((i & L) == 0);
    unsigned long long va = keys[i], vb = keys[j];
    bool sw = desc ? (va < vb) : (va > vb);
    if (sw) { keys[i] = vb; keys[j] = va; }
}

__global__ __launch_bounds__(1024) void bitonic_lmerge8k(
    unsigned long long* keys, int L,
    const float4* __restrict__ boxes, float4* __restrict__ box_s,
    unsigned long long* __restrict__ validw)
{
    __shared__ unsigned long long s[8192];
    const int base = blockIdx.x * 8192, t = threadIdx.x;
    for (int k = t; k < 8192; k += 1024) s[k] = keys[base + k];
    const bool desc = ((base & L) == 0);
    for (int d = 4096; d >= 1; d >>= 1) {
        __syncthreads();
        for (int pr = t; pr < 4096; pr += 1024) {
            int i = ((pr & ~(d - 1)) << 1) | (pr & (d - 1));
            int j = i + d;
            unsigned long long va = s[i], vb = s[j];
            bool sw = desc ? (va < vb) : (va > vb);
            if (sw) { s[i] = vb; s[j] = va; }
        }
    }
    __syncthreads();
    for (int k = t; k < 8192; k += 1024) keys[base + k] = s[k];
    // final merge, block 0: s[0..8191] is the global top-8192 (descending) —
    // fused gather of the top-PRE boxes + min-size valid ballot.
    if (L == SORTN && blockIdx.x == 0) {
        for (int k = t; k < 6144; k += 1024) {
            bool valid = false;
            if (k < PRE) {
                unsigned idx = (unsigned)(s[k] & 0xffffffffull);
                float4 b = boxes[idx];
                box_s[k] = b;
                valid = ((b.z - b.x) >= 16.f) && ((b.w - b.y) >= 16.f);
            }
            unsigned long long bal = __ballot(valid);
            if ((t & 63) == 0) validw[k >> 6] = bal;
        }
    }
}

// ---------------------------------------------------------------------------
__global__ __launch_bounds__(128) void nms_mask(
    const float4* __restrict__ box_s, unsigned long long* __restrict__ mask)
{
    const int i = blockIdx.x;
    const int w = threadIdx.x;
    if (w >= NW) return;
    float4 bi = box_s[i];
    float areai = (bi.z - bi.x) * (bi.w - bi.y);
    unsigned long long m = 0ull;
    const int j0 = w * 64;
    if (j0 + 63 > i) {
#pragma unroll 4
        for (int b = 0; b < 64; ++b) {
            int j = j0 + b;
            if (j <= i || j >= PRE) continue;
            float4 bj = box_s[j];
            float areaj = (bj.z - bj.x) * (bj.w - bj.y);
            float iy1 = fmaxf(bi.x, bj.x), ix1 = fmaxf(bi.y, bj.y);
            float iy2 = fminf(bi.z, bj.z), ix2 = fminf(bi.w, bj.w);
            float inter = fmaxf(iy2 - iy1, 0.f) * fmaxf(ix2 - ix1, 0.f);
            float iou = inter / (areai + areaj - inter + 1e-8f);
            if (iou > 0.7f) m |= (1ull << b);
        }
    }
    mask[(size_t)i * MASKW + w] = m;
}

// ---------------------------------------------------------------------------
// nms_scan (+fused out_gather)
// ---------------------------------------------------------------------------
__global__ __launch_bounds__(256) void nms_scan_out(
    const unsigned long long* __restrict__ mask,
    const unsigned long long* __restrict__ validw,
    const float4* __restrict__ box_s, float* __restrict__ outp)
{
    __shared__ unsigned long long kw_s[NW];
    __shared__ int prefix[NW];
    const int t = threadIdx.x;
    if (t < 64) {
        const int l = t;
        unsigned long long r0 = ~validw[l];
        unsigned long long r1 = (l < NW - 64) ? ~validw[64 + l] : ~0ull;
        unsigned long long p0[16], p1[16];
#pragma unroll
        for (int k = 0; k < 16; ++k) {
            p0[k] = mask[(size_t)k * MASKW + l];
            p1[k] = (l < NW - 64) ? mask[(size_t)k * MASKW + 64 + l] : 0ull;
        }
        int kept = 0;
        for (int w = 0; w < NW && kept < POST; ++w) {
            unsigned long long Wc = (w < 64) ? __shfl(r0, w) : __shfl(r1, w - 64);
#pragma unroll 16
            for (int b = 0; b < 64; ++b) {
                int i = w * 64 + b;
                if (i >= PRE) break;
                int slot = i & 15;
                unsigned long long m0 = p0[slot], m1 = p1[slot];
                int nxt = i + 16;
                if (nxt < PRE) {
                    p0[slot] = mask[(size_t)nxt * MASKW + l];
                    p1[slot] = (l < NW - 64) ? mask[(size_t)nxt * MASKW + 64 + l] : 0ull;
                }
                if (!((Wc >> b) & 1ull)) {
                    r0 |= m0; r1 |= m1;
                    Wc = (w < 64) ? __shfl(r0, w) : __shfl(r1, w - 64);
                    ++kept;
                }
            }
        }
        kw_s[l] = ~r0;
        if (l < NW - 64) kw_s[64 + l] = ~r1;
    }
    __syncthreads();
    if (t == 0) {
        int cum = 0;
        for (int w = 0; w < NW; ++w) { prefix[w] = cum; cum += __popcll(kw_s[w]); }
    }
    for (int k = t; k < POST * 4; k += 256) outp[k] = 0.f;
    __syncthreads();
    for (int i = t; i < PRE; i += 256) {
        int w = i >> 6, b = i & 63;
        unsigned long long kw = kw_s[w];
        if ((kw >> b) & 1ull) {
            int rank = prefix[w] + __popcll(kw & ((1ull << b) - 1ull));
            if (rank < POST) {
                float4 bx = box_s[i];
                outp[rank * 4 + 0] = bx.x;
                outp[rank * 4 + 1] = bx.y;
                outp[rank * 4 + 2] = bx.z;
                outp[rank * 4 + 3] = bx.w;
            }
        }
    }
}

// ---------------------------------------------------------------------------
extern "C" void kernel_launch(void* const* d_in, const int* in_sizes, int n_in,
                              void* d_out, int out_size, void* d_ws, size_t ws_size,
                              hipStream_t stream)
{
    const float* x      = (const float*)d_in[0];
    const int*   ishape = (const int*)  d_in[1];
    const float* am     = (const float*)d_in[2];
    const float* w1   = (const float*)d_in[6];
    const float* b1   = (const float*)d_in[7];
    const float* wcls = (const float*)d_in[8];
    const float* bcls = (const float*)d_in[9];
    const float* wbox = (const float*)d_in[10];
    const float* bbox = (const float*)d_in[11];
    float* out = (float*)d_out;

    char* ws = (char*)d_ws;
    size_t off = 0;
    float* y  = (float*)(ws + off);  off += (size_t)COUT * NPIX * 4;
    u16* xt1  = (u16*)(ws + off);    off += (size_t)SPAD * 1024 * 2;
    u16* xt2  = (u16*)(ws + off);    off += (size_t)SPAD * 1024 * 2;
    u16* wp1  = (u16*)(ws + off);    off += (size_t)9 * COUT * 1024 * 2;
    u16* wp2  = (u16*)(ws + off);    off += (size_t)9 * COUT * 1024 * 2;
    float4* boxes = (float4*)(ws + off);              off += (size_t)NANCH * 16;
    unsigned long long* keys = (unsigned long long*)(ws + off); off += (size_t)SORTN * 8;
    float4* box_s = (float4*)(ws + off);              off += (size_t)PRE * 16;
    unsigned long long* validw = (unsigned long long*)(ws + off); off += 96 * 8;
    unsigned long long* maskb  = (unsigned long long*)(ws + off); off += (size_t)PRE * MASKW * 8;
    float* wh = (float*)(ws + off);  off += (size_t)CIN * KH * 4;

    xsplit<<<dim3(414, 4), 256, 0, stream>>>(x, xt1, xt2);
    wsplit<<<COUT + (CIN * KH + 255) / 256, 256, 0, stream>>>(w1, wp1, wp2, wcls, wbox, wh);
    conv_mfma<<<dim3(4, (NPIX + PXT - 1) / PXT), 512, 0, stream>>>(xt1, xt2, wp1, wp2, b1, y);
    rpn_head<<<HEADB + (SORTN - NANCH + 255) / 256, 256, 0, stream>>>(
        y, wh, bcls, bbox, am, ishape, out, out + NANCH, boxes, keys);
    bitonic_local8k<<<SORTN / 8192, 1024, 0, stream>>>(keys);
    for (int L = 16384; L <= SORTN; L <<= 1) {
        for (int d = L >> 1; d >= 8192; d >>= 1)
            bitonic_gpass<<<SORTN / 512, 256, 0, stream>>>(keys, L, d);
        bitonic_lmerge8k<<<SORTN / 8192, 1024, 0, stream>>>(keys, L, boxes, box_s, validw);
    }
    nms_mask<<<PRE, 128, 0, stream>>>(box_s, maskb);
    nms_scan_out<<<1, 256, 0, stream>>>(maskb, validw, box_s, out + (size_t)NANCH * 5);
}